// Round 8
// baseline (109.984 us; speedup 1.0000x reference)
//
#include <hip/hip_runtime.h>
#include <hip/hip_bf16.h>
#include <stdint.h>

// SketchConv2d: out = conv2d(x, Weff) + bias, where
// Weff[o,f] = (1/4) * sum_{n,s} sketches[n,f,s] * signed[n,s,o]
// f channel-major flat (c*9 + kh*3 + kw).
//
// B=32, CIN=128, H=W=64, OUT=256, KH=KW=3, H2=W2=62, NSK=4, SDIM=128.
//
// Round 8: r7 geometry + TRUE counted-vmcnt pipeline (T3/T4).
//  - K split into 36 BK=32 steps; A-tile 16 KB, TRIPLE-buffered (48 KB).
//  - per step: s_waitcnt vmcnt(2) [own stage(s) done; stage(s+1) flying]
//    -> s_barrier [publishes buf s%3 to all; certifies everyone done
//    reading buf (s-1)%3] -> STAGE(s+2) into buf (s+2)%3 (== (s-1)%3)
//    -> 12 ds_read_b128 + 32 MFMA (compiler lgkm interleave), setprio.
//    ONE barrier/step, vmcnt never drains to 0 until the last step.
//  - B: 6 x-rows staged once, [6][64 j][256 B] bf16 swizzled (96 KB).
//  LDS = 48 + 96 = 144 KB. Grid = 512 blocks (2 clean CU rounds).

#define BATCH 32
#define CIN   128
#define HH    64
#define WW    64
#define OUTC  256
#define H2    62
#define W2    62
#define A_TILE 16384                  // 256 o x 32 k x 2B per BK=32 step
#define WS_A_BYTES (36 * A_TILE)      // 576 KB
#define BROWB 16384                   // 64 j * 256 B per x-row

typedef __bf16 bf16x8 __attribute__((ext_vector_type(8)));
typedef float  f32x4  __attribute__((ext_vector_type(4)));

typedef unsigned int u32_as1 __attribute__((address_space(1)));
typedef unsigned int u32_as3 __attribute__((address_space(3)));

__device__ __forceinline__ void async_copy16(const void* g, void* l) {
  __builtin_amdgcn_global_load_lds((const u32_as1*)g, (u32_as3*)l, 16, 0, 0);
}

// ---------------------------------------------------------------------------
// Kernel 1: Weff -> 36 pre-swizzled BK=32 tile images in ws.
// st = (kh*3+kw)*4 + (c>>5), kk = c&31;
// byte = st*16384 + o*64 + ((kk*2) ^ ((o&3)<<4) ^ ((o&4)<<2)).
// ---------------------------------------------------------------------------
#define FPB 4
__global__ __launch_bounds__(256) void weff_kernel(
    const float* __restrict__ sketches,   // (4, 1152, 128)
    const float* __restrict__ sgn,        // (4, 128, 256)
    char* __restrict__ wsA)
{
  __shared__ alignas(16) float sk[512 * FPB];
  const int f0 = blockIdx.x * FPB;
  const int t  = threadIdx.x;

  for (int k = 0; k < (512 * FPB) / 256; ++k) {
    int idx = t + k * 256;
    int fi  = idx >> 9;
    int ns  = idx & 511;
    int n   = ns >> 7;
    int s   = ns & 127;
    sk[ns * FPB + fi] = sketches[(n * 1152 + f0 + fi) * 128 + s];
  }
  __syncthreads();

  const int o = t;
  float acc0 = 0.f, acc1 = 0.f, acc2 = 0.f, acc3 = 0.f;
#pragma unroll 8
  for (int ns = 0; ns < 512; ++ns) {
    float sg = sgn[ns * 256 + o];
    f32x4 skv = *(const f32x4*)(&sk[ns * FPB]);
    acc0 += sg * skv[0];
    acc1 += sg * skv[1];
    acc2 += sg * skv[2];
    acc3 += sg * skv[3];
  }

  float accs[FPB] = {acc0, acc1, acc2, acc3};
#pragma unroll
  for (int fi = 0; fi < FPB; ++fi) {
    int f    = f0 + fi;
    int c    = f / 9;
    int khkw = f - c * 9;
    int st   = khkw * 4 + (c >> 5);
    int kk   = c & 31;
    uint32_t byteoff = (uint32_t)st * A_TILE + (uint32_t)o * 64
                     + (((uint32_t)kk * 2u) ^ (uint32_t)((o & 3) << 4)
                                            ^ (uint32_t)((o & 4) << 2));
    *(__hip_bfloat16*)(wsA + byteoff) = __float2bfloat16(accs[fi] * 0.25f);
  }
}

// ---------------------------------------------------------------------------
// Kernel 2: implicit-GEMM conv, 3-buffered counted-vmcnt K-loop (36 steps).
// Block (b, ig): 256 o x 256 e (4 i-rows x 64 j), 8 waves (512 thr).
// wave: wo = w>>2 (o-half of 128), we = w&3 (i-row).
// ---------------------------------------------------------------------------
__global__ __launch_bounds__(512, 2) void conv_kernel(
    const float* __restrict__ x,
    const char*  __restrict__ wA,
    const float* __restrict__ bias,
    float* __restrict__ out)
{
  __shared__ alignas(16) char lds[3 * A_TILE + 6 * BROWB];  // 48 + 96 KB
  char* ldsA = lds;
  char* ldsB = lds + 3 * A_TILE;

  const int bid = blockIdx.x;
  const int swz = (bid & 7) * 64 + (bid >> 3);    // 512 = 8*64, bijective
  const int b   = swz >> 4;
  const int ig  = swz & 15;
  const int i0  = ig * 4;

  const int t    = threadIdx.x;
  const int lane = t & 63;
  const int w    = t >> 6;       // 0..7
  const int wo   = w >> 2;       // o-half (128 o's)
  const int we   = w & 3;        // i-row within group

  // stage one 16 KB A image: 2 x 1KB glds per wave
#define STAGE_A(ST, BUF) do {                                              \
    const char* asrc_ = wA + (size_t)(ST) * A_TILE + w * 2048 + lane * 16; \
    char* adst_ = ldsA + (BUF) * A_TILE + w * 2048;                        \
    async_copy16(asrc_,         adst_);                                    \
    async_copy16(asrc_ + 1024,  adst_ + 1024);                             \
  } while (0)

  STAGE_A(0, 0);
  STAGE_A(1, 1);   // both in flight across the whole B staging

  // ---- stage B once: x[b, :, i0..i0+5 (clamped), :] -> [r][j][c] bf16, swz
  {
    const int j  = t & 63;
    const int cq = t >> 6;                         // 8 groups of 16 channels
    const uint32_t swb = (uint32_t)((j & 7) << 4);
#pragma unroll
    for (int r = 0; r < 6; ++r) {
      int xrow = i0 + r; if (xrow > 63) xrow = 63;
      const float* xr = x + (((size_t)(b * CIN + cq * 16)) * HH + xrow) * WW + j;
      char* lrow = ldsB + r * BROWB + j * 256;
#pragma unroll
      for (int g = 0; g < 2; ++g) {
        bf16x8 pk;
#pragma unroll
        for (int cc = 0; cc < 8; ++cc)
          pk[cc] = (__bf16)xr[(size_t)(g * 8 + cc) * (HH * WW)];
        uint32_t c0b = (uint32_t)(cq * 32 + g * 16);
        *(bf16x8*)(lrow + (c0b ^ swb)) = pk;
      }
    }
  }

  f32x4 acc[8][4];
  const f32x4 zf = {0.f, 0.f, 0.f, 0.f};
#pragma unroll
  for (int mi = 0; mi < 8; ++mi)
#pragma unroll
    for (int ni = 0; ni < 4; ++ni)
      acc[mi][ni] = zf;

  // ---- per-lane LDS read bases
  const int ln15  = lane & 15;
  const int khi16 = (lane >> 4) << 4;              // byte of 8-elem k-group
  // A: row = wo*128 + mi*16 + ln15 (64 B rows); byte = khi16 ^ swzA(row)
  const char* pA = ldsA + (wo * 128 + ln15) * 64
                 + (((uint32_t)khi16) ^ ((uint32_t)((ln15 & 3) << 4))
                                      ^ ((uint32_t)((ln15 & 4) << 2)));

  // B: byte-in-row = CSH*128 + [(cs&1)^((col>>2)&1)]*64
  //                + (khi16 ^ ((col&3)<<4));  row = (we+kh)*BROWB + col*256
#define MKB(COL, PAR) (ldsB + we * BROWB + (COL) * 256                     \
    + (((uint32_t)khi16) ^ ((uint32_t)(((COL) & 3) << 4)))                 \
    + (uint32_t)((((PAR) ^ (((COL) >> 2) & 1)) & 1) * 64))
  const char* pB0E = MKB(ln15 + 0, 0); const char* pB0O = MKB(ln15 + 0, 1);
  const char* pB1E = MKB(ln15 + 1, 0); const char* pB1O = MKB(ln15 + 1, 1);
  const char* pB2E = MKB(ln15 + 2, 0); const char* pB2O = MKB(ln15 + 2, 1);
  const int c30 = (48 + ln15 + 0 > 63) ? 63 : 48 + ln15 + 0;
  const int c31 = (48 + ln15 + 1 > 63) ? 63 : 48 + ln15 + 1;
  const int c32 = (48 + ln15 + 2 > 63) ? 63 : 48 + ln15 + 2;
  const char* pC0E = MKB(c30, 0); const char* pC0O = MKB(c30, 1);
  const char* pC1E = MKB(c31, 0); const char* pC1O = MKB(c31, 1);
  const char* pC2E = MKB(c32, 0); const char* pC2O = MKB(c32, 1);
#undef MKB

  // own B ds_writes retired before first barrier
  asm volatile("s_waitcnt lgkmcnt(0)" ::: "memory");

#define MFMA_ __builtin_amdgcn_mfma_f32_16x16x32_bf16
#define WVM2 asm volatile("s_waitcnt vmcnt(2)" ::: "memory")
#define WVM0 asm volatile("s_waitcnt vmcnt(0)" ::: "memory")

  // one BK=32 step. WAR proof: barrier certifies all waves issued step
  // s-1's MFMAs (=> their ds_reads of buf (s-1)%3 completed), and TGT ==
  // (s-1)%3; publish proof: each wave did vmcnt(2) [own stage(s) done]
  // before its barrier.
#define STEP(ST, KH, KW, CSH, PAR, BUF, TGT, WVM) do {                     \
    WVM;                                                                   \
    __builtin_amdgcn_s_barrier();                                          \
    if ((ST) < 34) STAGE_A((ST) + 2, TGT);                                 \
    const int bimm_ = (KH) * BROWB + (CSH) * 128;                          \
    const int aimm_ = (BUF) * A_TILE;                                      \
    bf16x8 b0_ = *(const bf16x8*)(pB##KW##PAR + bimm_);                    \
    bf16x8 b1_ = *(const bf16x8*)(pB##KW##PAR + bimm_ + 4096);             \
    bf16x8 b2_ = *(const bf16x8*)(pB##KW##PAR + bimm_ + 8192);             \
    bf16x8 b3_ = *(const bf16x8*)(pC##KW##PAR + bimm_);                    \
    bf16x8 a0_ = *(const bf16x8*)(pA + aimm_);                             \
    bf16x8 a1_ = *(const bf16x8*)(pA + aimm_ + 1024);                      \
    bf16x8 a2_ = *(const bf16x8*)(pA + aimm_ + 2048);                      \
    bf16x8 a3_ = *(const bf16x8*)(pA + aimm_ + 3072);                      \
    bf16x8 a4_ = *(const bf16x8*)(pA + aimm_ + 4096);                      \
    bf16x8 a5_ = *(const bf16x8*)(pA + aimm_ + 5120);                      \
    bf16x8 a6_ = *(const bf16x8*)(pA + aimm_ + 6144);                      \
    bf16x8 a7_ = *(const bf16x8*)(pA + aimm_ + 7168);                      \
    __builtin_amdgcn_s_setprio(1);                                         \
    acc[0][0] = MFMA_(a0_, b0_, acc[0][0], 0, 0, 0);                       \
    acc[0][1] = MFMA_(a0_, b1_, acc[0][1], 0, 0, 0);                       \
    acc[0][2] = MFMA_(a0_, b2_, acc[0][2], 0, 0, 0);                       \
    acc[0][3] = MFMA_(a0_, b3_, acc[0][3], 0, 0, 0);                       \
    acc[1][0] = MFMA_(a1_, b0_, acc[1][0], 0, 0, 0);                       \
    acc[1][1] = MFMA_(a1_, b1_, acc[1][1], 0, 0, 0);                       \
    acc[1][2] = MFMA_(a1_, b2_, acc[1][2], 0, 0, 0);                       \
    acc[1][3] = MFMA_(a1_, b3_, acc[1][3], 0, 0, 0);                       \
    acc[2][0] = MFMA_(a2_, b0_, acc[2][0], 0, 0, 0);                       \
    acc[2][1] = MFMA_(a2_, b1_, acc[2][1], 0, 0, 0);                       \
    acc[2][2] = MFMA_(a2_, b2_, acc[2][2], 0, 0, 0);                       \
    acc[2][3] = MFMA_(a2_, b3_, acc[2][3], 0, 0, 0);                       \
    acc[3][0] = MFMA_(a3_, b0_, acc[3][0], 0, 0, 0);                       \
    acc[3][1] = MFMA_(a3_, b1_, acc[3][1], 0, 0, 0);                       \
    acc[3][2] = MFMA_(a3_, b2_, acc[3][2], 0, 0, 0);                       \
    acc[3][3] = MFMA_(a3_, b3_, acc[3][3], 0, 0, 0);                       \
    acc[4][0] = MFMA_(a4_, b0_, acc[4][0], 0, 0, 0);                       \
    acc[4][1] = MFMA_(a4_, b1_, acc[4][1], 0, 0, 0);                       \
    acc[4][2] = MFMA_(a4_, b2_, acc[4][2], 0, 0, 0);                       \
    acc[4][3] = MFMA_(a4_, b3_, acc[4][3], 0, 0, 0);                       \
    acc[5][0] = MFMA_(a5_, b0_, acc[5][0], 0, 0, 0);                       \
    acc[5][1] = MFMA_(a5_, b1_, acc[5][1], 0, 0, 0);                       \
    acc[5][2] = MFMA_(a5_, b2_, acc[5][2], 0, 0, 0);                       \
    acc[5][3] = MFMA_(a5_, b3_, acc[5][3], 0, 0, 0);                       \
    acc[6][0] = MFMA_(a6_, b0_, acc[6][0], 0, 0, 0);                       \
    acc[6][1] = MFMA_(a6_, b1_, acc[6][1], 0, 0, 0);                       \
    acc[6][2] = MFMA_(a6_, b2_, acc[6][2], 0, 0, 0);                       \
    acc[6][3] = MFMA_(a6_, b3_, acc[6][3], 0, 0, 0);                       \
    acc[7][0] = MFMA_(a7_, b0_, acc[7][0], 0, 0, 0);                       \
    acc[7][1] = MFMA_(a7_, b1_, acc[7][1], 0, 0, 0);                       \
    acc[7][2] = MFMA_(a7_, b2_, acc[7][2], 0, 0, 0);                       \
    acc[7][3] = MFMA_(a7_, b3_, acc[7][3], 0, 0, 0);                       \
    __builtin_amdgcn_s_setprio(0);                                         \
  } while (0)

  STEP(0,  0,0, 0,E, 0, 2, WVM2);  STEP(1,  0,0, 0,O, 1, 0, WVM2);
  STEP(2,  0,0, 1,E, 2, 1, WVM2);  STEP(3,  0,0, 1,O, 0, 2, WVM2);
  STEP(4,  0,1, 0,E, 1, 0, WVM2);  STEP(5,  0,1, 0,O, 2, 1, WVM2);
  STEP(6,  0,1, 1,E, 0, 2, WVM2);  STEP(7,  0,1, 1,O, 1, 0, WVM2);
  STEP(8,  0,2, 0,E, 2, 1, WVM2);  STEP(9,  0,2, 0,O, 0, 2, WVM2);
  STEP(10, 0,2, 1,E, 1, 0, WVM2);  STEP(11, 0,2, 1,O, 2, 1, WVM2);
  STEP(12, 1,0, 0,E, 0, 2, WVM2);  STEP(13, 1,0, 0,O, 1, 0, WVM2);
  STEP(14, 1,0, 1,E, 2, 1, WVM2);  STEP(15, 1,0, 1,O, 0, 2, WVM2);
  STEP(16, 1,1, 0,E, 1, 0, WVM2);  STEP(17, 1,1, 0,O, 2, 1, WVM2);
  STEP(18, 1,1, 1,E, 0, 2, WVM2);  STEP(19, 1,1, 1,O, 1, 0, WVM2);
  STEP(20, 1,2, 0,E, 2, 1, WVM2);  STEP(21, 1,2, 0,O, 0, 2, WVM2);
  STEP(22, 1,2, 1,E, 1, 0, WVM2);  STEP(23, 1,2, 1,O, 2, 1, WVM2);
  STEP(24, 2,0, 0,E, 0, 2, WVM2);  STEP(25, 2,0, 0,O, 1, 0, WVM2);
  STEP(26, 2,0, 1,E, 2, 1, WVM2);  STEP(27, 2,0, 1,O, 0, 2, WVM2);
  STEP(28, 2,1, 0,E, 1, 0, WVM2);  STEP(29, 2,1, 0,O, 2, 1, WVM2);
  STEP(30, 2,1, 1,E, 0, 2, WVM2);  STEP(31, 2,1, 1,O, 1, 0, WVM2);
  STEP(32, 2,2, 0,E, 2, 1, WVM2);  STEP(33, 2,2, 0,O, 0, 2, WVM2);
  STEP(34, 2,2, 1,E, 1, 0, WVM2);  STEP(35, 2,2, 1,O, 2, 1, WVM0);

#undef STEP
#undef WVM0
#undef WVM2
#undef MFMA_
#undef STAGE_A

  // ---- epilogue: D[m][n]: m=(lane>>4)*4+reg, n=lane&15
  const int jn   = ln15;
  const int g4   = lane >> 4;
  const int irow = i0 + we;
  if (irow < H2) {
#pragma unroll
    for (int mi = 0; mi < 8; ++mi) {
#pragma unroll
      for (int ni = 0; ni < 4; ++ni) {
        const int jj = (ni << 4) + jn;
        if (jj < W2) {
#pragma unroll
          for (int rr = 0; rr < 4; ++rr) {
            const int o = (wo << 7) + (mi << 4) + (g4 << 2) + rr;
            out[(((size_t)b * OUTC + o) * H2 + irow) * W2 + jj] =
                acc[mi][ni][rr] + bias[o];
          }
        }
      }
    }
  }
}

extern "C" void kernel_launch(void* const* d_in, const int* in_sizes, int n_in,
                              void* d_out, int out_size, void* d_ws, size_t ws_size,
                              hipStream_t stream) {
  const float* x        = (const float*)d_in[0];
  const float* sketches = (const float*)d_in[1];
  const float* sgn      = (const float*)d_in[2];
  const float* bias     = (const float*)d_in[3];
  float* out            = (float*)d_out;
  char* wsA             = (char*)d_ws;

  if (ws_size < (size_t)WS_A_BYTES) return;  // need 576 KB scratch

  weff_kernel<<<1152 / FPB, 256, 0, stream>>>(sketches, sgn, wsA);
  conv_kernel<<<BATCH * 16, 512, 0, stream>>>(x, wsA, bias, out);
}

// Round 9
// 104.988 us; speedup vs baseline: 1.0476x; 1.0476x over previous
//
#include <hip/hip_runtime.h>
#include <hip/hip_bf16.h>
#include <stdint.h>

// SketchConv2d: out = conv2d(x, Weff) + bias, where
// Weff[o,f] = (1/4) * sum_{n,s} sketches[n,f,s] * signed[n,s,o]
// f channel-major flat (c*9 + kh*3 + kw).
//
// B=32, CIN=128, H=W=64, OUT=256, KH=KW=3, H2=W2=62, NSK=4, SDIM=128.
//
// Round 9: software-pipelined K-loop (prefetch-regs one step ahead).
//  - A image FRAGMENT-LINEAR per BK=32 step: [st][og 16][lane 64][16B];
//    wave ds_read = base + lane*16 (2-way banks, no swizzle; glds linear).
//  - 36 steps; A 4-buffered (64 KB) + B 6 rows (96 KB) = 160 KB LDS.
//  - step s: vmcnt(2) -> s_barrier -> STAGE(s+3) -> PREFETCH regs(s+1)
//    -> 32 MFMA on regs(s).  Reads & MFMAs independent -> both pipes busy.
//  - two named register sets (static indexing, rule #20).

#define BATCH 32
#define CIN   128
#define HH    64
#define WW    64
#define OUTC  256
#define H2    62
#define W2    62
#define A_TILE 16384                  // 256 o x 32 k x 2B per BK=32 step
#define WS_A_BYTES (36 * A_TILE)      // 576 KB
#define BROWB 16384                   // 64 j * 256 B per x-row

typedef __bf16 bf16x8 __attribute__((ext_vector_type(8)));
typedef float  f32x4  __attribute__((ext_vector_type(4)));

typedef unsigned int u32_as1 __attribute__((address_space(1)));
typedef unsigned int u32_as3 __attribute__((address_space(3)));

__device__ __forceinline__ void async_copy16(const void* g, void* l) {
  __builtin_amdgcn_global_load_lds((const u32_as1*)g, (u32_as3*)l, 16, 0, 0);
}

// ---------------------------------------------------------------------------
// Kernel 1: Weff -> 36 fragment-linear BK=32 images in ws.
// st = tap*4 + (c>>5), tap = kh*3+kw, kk = c&31:
// byte = st*16384 + (o>>4)*1024 + ((kk>>3)*16 + (o&15))*16 + (kk&7)*2
// (content of lane l, elem e: A[o = og*16+(l&15)][c = ck*32 + (l>>4)*8 + e])
// ---------------------------------------------------------------------------
#define FPB 4
__global__ __launch_bounds__(256) void weff_kernel(
    const float* __restrict__ sketches,   // (4, 1152, 128)
    const float* __restrict__ sgn,        // (4, 128, 256)
    char* __restrict__ wsA)
{
  __shared__ alignas(16) float sk[512 * FPB];
  const int f0 = blockIdx.x * FPB;
  const int t  = threadIdx.x;

  for (int k = 0; k < (512 * FPB) / 256; ++k) {
    int idx = t + k * 256;
    int fi  = idx >> 9;
    int ns  = idx & 511;
    int n   = ns >> 7;
    int s   = ns & 127;
    sk[ns * FPB + fi] = sketches[(n * 1152 + f0 + fi) * 128 + s];
  }
  __syncthreads();

  const int o = t;
  float acc0 = 0.f, acc1 = 0.f, acc2 = 0.f, acc3 = 0.f;
#pragma unroll 8
  for (int ns = 0; ns < 512; ++ns) {
    float sg = sgn[ns * 256 + o];
    f32x4 skv = *(const f32x4*)(&sk[ns * FPB]);
    acc0 += sg * skv[0];
    acc1 += sg * skv[1];
    acc2 += sg * skv[2];
    acc3 += sg * skv[3];
  }

  float accs[FPB] = {acc0, acc1, acc2, acc3};
#pragma unroll
  for (int fi = 0; fi < FPB; ++fi) {
    int f   = f0 + fi;
    int c   = f / 9;
    int tap = f - c * 9;
    int st  = tap * 4 + (c >> 5);
    int kk  = c & 31;
    uint32_t byteoff = (uint32_t)st * A_TILE + (uint32_t)(o >> 4) * 1024
                     + (uint32_t)(((kk >> 3) * 16 + (o & 15)) * 16)
                     + (uint32_t)((kk & 7) * 2);
    *(__hip_bfloat16*)(wsA + byteoff) = __float2bfloat16(accs[fi] * 0.25f);
  }
}

// ---------------------------------------------------------------------------
// Kernel 2: implicit-GEMM conv, prefetch-pipelined 36-step K-loop.
// Block (b, ig): 256 o x 256 e (4 i-rows x 64 j), 8 waves (512 thr).
// wave: wo = w>>2 (o-half of 128), we = w&3 (i-row).
// ---------------------------------------------------------------------------
__global__ __launch_bounds__(512, 2) void conv_kernel(
    const float* __restrict__ x,
    const char*  __restrict__ wA,
    const float* __restrict__ bias,
    float* __restrict__ out)
{
  __shared__ alignas(16) char lds[4 * A_TILE + 6 * BROWB];  // 64 + 96 KB
  char* ldsA = lds;
  char* ldsB = lds + 4 * A_TILE;

  const int bid = blockIdx.x;
  const int swz = (bid & 7) * 64 + (bid >> 3);    // 512 = 8*64, bijective
  const int b   = swz >> 4;
  const int ig  = swz & 15;
  const int i0  = ig * 4;

  const int t    = threadIdx.x;
  const int lane = t & 63;
  const int w    = t >> 6;       // 0..7
  const int wo   = w >> 2;       // o-half (128 o's)
  const int we   = w & 3;        // i-row within group

  // stage one 16 KB A image: 2 x glds per wave (linear, no swizzle)
#define STAGE_A(ST, BUF) do {                                              \
    const char* asrc_ = wA + (size_t)(ST) * A_TILE + w * 2048 + lane * 16; \
    char* adst_ = ldsA + (BUF) * A_TILE + w * 2048;                        \
    async_copy16(asrc_,         adst_);                                    \
    async_copy16(asrc_ + 1024,  adst_ + 1024);                             \
  } while (0)

  STAGE_A(0, 0);
  STAGE_A(1, 1);
  STAGE_A(2, 2);   // 6 loads in flight across the whole B staging

  // ---- stage B once: x[b, :, i0..i0+5 (clamped), :] -> [r][j][c] bf16, swz
  {
    const int j  = t & 63;
    const int cq = t >> 6;                         // 8 groups of 16 channels
    const uint32_t swb = (uint32_t)((j & 7) << 4);
#pragma unroll
    for (int r = 0; r < 6; ++r) {
      int xrow = i0 + r; if (xrow > 63) xrow = 63;
      const float* xr = x + (((size_t)(b * CIN + cq * 16)) * HH + xrow) * WW + j;
      char* lrow = ldsB + r * BROWB + j * 256;
#pragma unroll
      for (int g = 0; g < 2; ++g) {
        bf16x8 pk;
#pragma unroll
        for (int cc = 0; cc < 8; ++cc)
          pk[cc] = (__bf16)xr[(size_t)(g * 8 + cc) * (HH * WW)];
        uint32_t c0b = (uint32_t)(cq * 32 + g * 16);
        *(bf16x8*)(lrow + (c0b ^ swb)) = pk;
      }
    }
  }

  f32x4 acc[8][4];
  const f32x4 zf = {0.f, 0.f, 0.f, 0.f};
#pragma unroll
  for (int mi = 0; mi < 8; ++mi)
#pragma unroll
    for (int ni = 0; ni < 4; ++ni)
      acc[mi][ni] = zf;

  // ---- per-lane LDS read bases
  const int ln15  = lane & 15;
  const int khi16 = (lane >> 4) << 4;              // byte of 8-elem k-group
  // A: fragment-linear; read = pA + buf*16384 + mi*1024
  const char* pA = ldsA + wo * 8192 + lane * 16;

  // B: row-major swizzled (r8-verified addressing)
#define MKB(COL, PAR) (ldsB + we * BROWB + (COL) * 256                     \
    + (((uint32_t)khi16) ^ ((uint32_t)(((COL) & 3) << 4)))                 \
    + (uint32_t)((((PAR) ^ (((COL) >> 2) & 1)) & 1) * 64))
  const char* pB0E = MKB(ln15 + 0, 0); const char* pB0O = MKB(ln15 + 0, 1);
  const char* pB1E = MKB(ln15 + 1, 0); const char* pB1O = MKB(ln15 + 1, 1);
  const char* pB2E = MKB(ln15 + 2, 0); const char* pB2O = MKB(ln15 + 2, 1);
  const int c30 = (48 + ln15 + 0 > 63) ? 63 : 48 + ln15 + 0;
  const int c31 = (48 + ln15 + 1 > 63) ? 63 : 48 + ln15 + 1;
  const int c32 = (48 + ln15 + 2 > 63) ? 63 : 48 + ln15 + 2;
  const char* pC0E = MKB(c30, 0); const char* pC0O = MKB(c30, 1);
  const char* pC1E = MKB(c31, 0); const char* pC1O = MKB(c31, 1);
  const char* pC2E = MKB(c32, 0); const char* pC2O = MKB(c32, 1);
#undef MKB

  // two prefetch register sets (static names: rule #20)
  bf16x8 A00, A01, A02, A03, A04, A05, A06, A07, B00, B01, B02, B03;
  bf16x8 A10, A11, A12, A13, A14, A15, A16, A17, B10, B11, B12, B13;

  // prefetch the 12 fragments of step ST into set P (A from buf BUF)
#define PRE(P, BUF, KH, KW, PAR, CSH) do {                                 \
    const int ab_ = (BUF) * A_TILE;                                        \
    A##P##0 = *(const bf16x8*)(pA + ab_);                                  \
    A##P##1 = *(const bf16x8*)(pA + ab_ + 1024);                           \
    A##P##2 = *(const bf16x8*)(pA + ab_ + 2048);                           \
    A##P##3 = *(const bf16x8*)(pA + ab_ + 3072);                           \
    A##P##4 = *(const bf16x8*)(pA + ab_ + 4096);                           \
    A##P##5 = *(const bf16x8*)(pA + ab_ + 5120);                           \
    A##P##6 = *(const bf16x8*)(pA + ab_ + 6144);                           \
    A##P##7 = *(const bf16x8*)(pA + ab_ + 7168);                           \
    const int bi_ = (KH) * BROWB + (CSH) * 128;                            \
    B##P##0 = *(const bf16x8*)(pB##KW##PAR + bi_);                         \
    B##P##1 = *(const bf16x8*)(pB##KW##PAR + bi_ + 4096);                  \
    B##P##2 = *(const bf16x8*)(pB##KW##PAR + bi_ + 8192);                  \
    B##P##3 = *(const bf16x8*)(pC##KW##PAR + bi_);                         \
  } while (0)

#define MFMA_ __builtin_amdgcn_mfma_f32_16x16x32_bf16
#define MM(P) do {                                                         \
    __builtin_amdgcn_s_setprio(1);                                         \
    acc[0][0] = MFMA_(A##P##0, B##P##0, acc[0][0], 0, 0, 0);               \
    acc[0][1] = MFMA_(A##P##0, B##P##1, acc[0][1], 0, 0, 0);               \
    acc[0][2] = MFMA_(A##P##0, B##P##2, acc[0][2], 0, 0, 0);               \
    acc[0][3] = MFMA_(A##P##0, B##P##3, acc[0][3], 0, 0, 0);               \
    acc[1][0] = MFMA_(A##P##1, B##P##0, acc[1][0], 0, 0, 0);               \
    acc[1][1] = MFMA_(A##P##1, B##P##1, acc[1][1], 0, 0, 0);               \
    acc[1][2] = MFMA_(A##P##1, B##P##2, acc[1][2], 0, 0, 0);               \
    acc[1][3] = MFMA_(A##P##1, B##P##3, acc[1][3], 0, 0, 0);               \
    acc[2][0] = MFMA_(A##P##2, B##P##0, acc[2][0], 0, 0, 0);               \
    acc[2][1] = MFMA_(A##P##2, B##P##1, acc[2][1], 0, 0, 0);               \
    acc[2][2] = MFMA_(A##P##2, B##P##2, acc[2][2], 0, 0, 0);               \
    acc[2][3] = MFMA_(A##P##2, B##P##3, acc[2][3], 0, 0, 0);               \
    acc[3][0] = MFMA_(A##P##3, B##P##0, acc[3][0], 0, 0, 0);               \
    acc[3][1] = MFMA_(A##P##3, B##P##1, acc[3][1], 0, 0, 0);               \
    acc[3][2] = MFMA_(A##P##3, B##P##2, acc[3][2], 0, 0, 0);               \
    acc[3][3] = MFMA_(A##P##3, B##P##3, acc[3][3], 0, 0, 0);               \
    acc[4][0] = MFMA_(A##P##4, B##P##0, acc[4][0], 0, 0, 0);               \
    acc[4][1] = MFMA_(A##P##4, B##P##1, acc[4][1], 0, 0, 0);               \
    acc[4][2] = MFMA_(A##P##4, B##P##2, acc[4][2], 0, 0, 0);               \
    acc[4][3] = MFMA_(A##P##4, B##P##3, acc[4][3], 0, 0, 0);               \
    acc[5][0] = MFMA_(A##P##5, B##P##0, acc[5][0], 0, 0, 0);               \
    acc[5][1] = MFMA_(A##P##5, B##P##1, acc[5][1], 0, 0, 0);               \
    acc[5][2] = MFMA_(A##P##5, B##P##2, acc[5][2], 0, 0, 0);               \
    acc[5][3] = MFMA_(A##P##5, B##P##3, acc[5][3], 0, 0, 0);               \
    acc[6][0] = MFMA_(A##P##6, B##P##0, acc[6][0], 0, 0, 0);               \
    acc[6][1] = MFMA_(A##P##6, B##P##1, acc[6][1], 0, 0, 0);               \
    acc[6][2] = MFMA_(A##P##6, B##P##2, acc[6][2], 0, 0, 0);               \
    acc[6][3] = MFMA_(A##P##6, B##P##3, acc[6][3], 0, 0, 0);               \
    acc[7][0] = MFMA_(A##P##7, B##P##0, acc[7][0], 0, 0, 0);               \
    acc[7][1] = MFMA_(A##P##7, B##P##1, acc[7][1], 0, 0, 0);               \
    acc[7][2] = MFMA_(A##P##7, B##P##2, acc[7][2], 0, 0, 0);               \
    acc[7][3] = MFMA_(A##P##7, B##P##3, acc[7][3], 0, 0, 0);               \
    __builtin_amdgcn_s_setprio(0);                                         \
  } while (0)

#define WVM2 asm volatile("s_waitcnt vmcnt(2)" ::: "memory")
#define WVM0 asm volatile("s_waitcnt vmcnt(0)" ::: "memory")

  // own B ds_writes retired, stage(0) landed, then publish to all waves
  asm volatile("s_waitcnt vmcnt(4) lgkmcnt(0)" ::: "memory");
  __builtin_amdgcn_s_barrier();

  PRE(0, 0, 0, 0, E, 0);   // fragments of step 0 (buf 0, kh0 kw0 ck0)

  // step s: certify stage(s+1) (vmcnt2: stage(s+2) may stay in flight) ->
  // barrier -> STAGE(s+3) into buf (s-1)%4 (reads retired: lgkm-drained
  // before MM(s-1), which precedes this barrier) -> PREFETCH step s+1 ->
  // MM on set s&1 (operands loaded in step s-1; compiler counts lgkm).
#define STEP(ST, CUR, NXT, KH, KW, PAR, CSH, WVM) do {                     \
    WVM;                                                                   \
    __builtin_amdgcn_s_barrier();                                          \
    if ((ST) + 3 <= 35) STAGE_A((ST) + 3, ((ST) + 3) & 3);                 \
    if ((ST) < 35) PRE(NXT, ((ST) + 1) & 3, KH, KW, PAR, CSH);             \
    MM(CUR);                                                               \
  } while (0)

  //   s  cur nxt  [--- step s+1 params: kh kw par csh ---]
  STEP(0,  0, 1,  0, 0, O, 0, WVM2);
  STEP(1,  1, 0,  0, 0, E, 1, WVM2);
  STEP(2,  0, 1,  0, 0, O, 1, WVM2);
  STEP(3,  1, 0,  0, 1, E, 0, WVM2);
  STEP(4,  0, 1,  0, 1, O, 0, WVM2);
  STEP(5,  1, 0,  0, 1, E, 1, WVM2);
  STEP(6,  0, 1,  0, 1, O, 1, WVM2);
  STEP(7,  1, 0,  0, 2, E, 0, WVM2);
  STEP(8,  0, 1,  0, 2, O, 0, WVM2);
  STEP(9,  1, 0,  0, 2, E, 1, WVM2);
  STEP(10, 0, 1,  0, 2, O, 1, WVM2);
  STEP(11, 1, 0,  1, 0, E, 0, WVM2);
  STEP(12, 0, 1,  1, 0, O, 0, WVM2);
  STEP(13, 1, 0,  1, 0, E, 1, WVM2);
  STEP(14, 0, 1,  1, 0, O, 1, WVM2);
  STEP(15, 1, 0,  1, 1, E, 0, WVM2);
  STEP(16, 0, 1,  1, 1, O, 0, WVM2);
  STEP(17, 1, 0,  1, 1, E, 1, WVM2);
  STEP(18, 0, 1,  1, 1, O, 1, WVM2);
  STEP(19, 1, 0,  1, 2, E, 0, WVM2);
  STEP(20, 0, 1,  1, 2, O, 0, WVM2);
  STEP(21, 1, 0,  1, 2, E, 1, WVM2);
  STEP(22, 0, 1,  1, 2, O, 1, WVM2);
  STEP(23, 1, 0,  2, 0, E, 0, WVM2);
  STEP(24, 0, 1,  2, 0, O, 0, WVM2);
  STEP(25, 1, 0,  2, 0, E, 1, WVM2);
  STEP(26, 0, 1,  2, 0, O, 1, WVM2);
  STEP(27, 1, 0,  2, 1, E, 0, WVM2);
  STEP(28, 0, 1,  2, 1, O, 0, WVM2);
  STEP(29, 1, 0,  2, 1, E, 1, WVM2);
  STEP(30, 0, 1,  2, 1, O, 1, WVM2);
  STEP(31, 1, 0,  2, 2, E, 0, WVM2);
  STEP(32, 0, 1,  2, 2, O, 0, WVM2);
  STEP(33, 1, 0,  2, 2, E, 1, WVM2);
  STEP(34, 0, 1,  2, 2, O, 1, WVM0);
  // step 35: no barrier needed (no further staging), just compute set 1
  MM(1);

#undef STEP
#undef WVM0
#undef WVM2
#undef MM
#undef MFMA_
#undef PRE
#undef STAGE_A

  // ---- epilogue: D[m][n]: m=(lane>>4)*4+reg, n=lane&15
  const int jn   = ln15;
  const int g4   = lane >> 4;
  const int irow = i0 + we;
  if (irow < H2) {
#pragma unroll
    for (int mi = 0; mi < 8; ++mi) {
#pragma unroll
      for (int ni = 0; ni < 4; ++ni) {
        const int jj = (ni << 4) + jn;
        if (jj < W2) {
#pragma unroll
          for (int rr = 0; rr < 4; ++rr) {
            const int o = (wo << 7) + (mi << 4) + (g4 << 2) + rr;
            out[(((size_t)b * OUTC + o) * H2 + irow) * W2 + jj] =
                acc[mi][ni][rr] + bias[o];
          }
        }
      }
    }
  }
}

extern "C" void kernel_launch(void* const* d_in, const int* in_sizes, int n_in,
                              void* d_out, int out_size, void* d_ws, size_t ws_size,
                              hipStream_t stream) {
  const float* x        = (const float*)d_in[0];
  const float* sketches = (const float*)d_in[1];
  const float* sgn      = (const float*)d_in[2];
  const float* bias     = (const float*)d_in[3];
  float* out            = (float*)d_out;
  char* wsA             = (char*)d_ws;

  if (ws_size < (size_t)WS_A_BYTES) return;  // need 576 KB scratch

  weff_kernel<<<1152 / FPB, 256, 0, stream>>>(sketches, sgn, wsA);
  conv_kernel<<<BATCH * 16, 512, 0, stream>>>(x, wsA, bias, out);
}